// Round 13
// baseline (136.561 us; speedup 1.0000x reference)
//
#include <hip/hip_runtime.h>

// Problem constants
#define D_B 8
#define N_T 2048
#define NN  64
#define N_H 8
#define N_C 32   // u-chunks of 64
#define NP  72   // padded LDS row stride (bf16): 144 B rows, 16B-aligned, 2-way alias (free)

typedef __bf16 bf16;
typedef bf16 bf16x8 __attribute__((ext_vector_type(8)));
typedef bf16 bf16x4 __attribute__((ext_vector_type(4)));
typedef float f32x4 __attribute__((ext_vector_type(4)));

static __device__ __forceinline__ f32x4 mfma16(bf16x8 a, bf16x8 b, f32x4 c) {
    // a_frag[j] = A[lane&15][(lane>>4)*8+j]; b_frag[j] = B[(lane>>4)*8+j][lane&15]
    // d[r] = D[(lane>>4)*4+r][lane&15]
    return __builtin_amdgcn_mfma_f32_16x16x32_bf16(a, b, c, 0, 0, 0);
}

static __device__ __forceinline__ bf16x8 ldcvt8(const float* p) {
    const f32x4 v0 = *(const f32x4*)p;
    const f32x4 v1 = *(const f32x4*)(p + 4);
    bf16x8 r;
#pragma unroll
    for (int k = 0; k < 4; k++) { r[k] = (bf16)v0[k]; r[4 + k] = (bf16)v1[k]; }
    return r;
}

// ---------------------------------------------------------------------------
// K1 (R10/R12-proven, ~4.5 us): block (b, c, qt) handles heads {2qt, 2qt+1}:
//   Qrd[b,c,h][u][i'] (direct store), Erd[b,c,h][i][u] (LDS-transposed flush),
//   dGq[b,c,qt][i][i'] (pre-transposed bf16), Rbf (qt==0).
// R A-frags direct from global fp32. 36.9 KB LDS -> 4 blocks/CU.
// Grid (D_B, N_C, 4): linear%8 = b (XCD-local).
// ---------------------------------------------------------------------------
__global__ __launch_bounds__(256, 4) void k_dg(
    const float* __restrict__ rp, const float* __restrict__ Qm,
    const float* __restrict__ Em,
    bf16* __restrict__ dGq, bf16* __restrict__ Rbf,
    bf16* __restrict__ Qrd, bf16* __restrict__ Erd)
{
    __shared__ bf16 Ql[64 * NP];   // Q_h [i'][j]
    __shared__ bf16 El[64 * NP];   // E_h [i][j]
    __shared__ bf16 QT[64 * NP];   // Qr tile [i'][u]; dG [i][i'] staging at tail
    __shared__ bf16 ET[64 * NP];   // Er tile [i][u]
    const int b = blockIdx.x, c = blockIdx.y, qt = blockIdx.z;
    const int tid = threadIdx.x;
    const int w = tid >> 6, l = tid & 63, q = l >> 4, l16 = l & 15;
    const int row = tid >> 2, col = (tid & 3) * 16;

    // R A-frags straight from global fp32 (rows u = c*64 + w*16 + l16)
    const float* rrow = rp + ((size_t)b * N_T + c * 64 + w * 16 + l16) * NN;
    const bf16x8 a0 = ldcvt8(rrow + q * 8);
    const bf16x8 a1 = ldcvt8(rrow + 32 + q * 8);

    if (qt == 0) {
        const float* src = rp + ((size_t)b * N_T + c * 64 + row) * NN + col;
        bf16* d = Rbf + ((size_t)b * N_T + c * 64 + row) * NN + col;
        *(bf16x8*)d       = ldcvt8(src);
        *(bf16x8*)(d + 8) = ldcvt8(src + 8);
    }

    f32x4 dacc[4];
#pragma unroll
    for (int ns = 0; ns < 4; ns++) { f32x4 z = {0.f, 0.f, 0.f, 0.f}; dacc[ns] = z; }

    for (int hh = 0; hh < 2; hh++) {
        const int h = qt * 2 + hh;
        {
            const float* qs = Qm + (size_t)h * 4096 + row * 64 + col;
            const float* es = Em + (size_t)h * 4096 + row * 64 + col;
            *(bf16x8*)&Ql[row * NP + col]     = ldcvt8(qs);
            *(bf16x8*)&Ql[row * NP + col + 8] = ldcvt8(qs + 8);
            *(bf16x8*)&El[row * NP + col]     = ldcvt8(es);
            *(bf16x8*)&El[row * NP + col + 8] = ldcvt8(es + 8);
        }
        __syncthreads();
        const size_t tb = (((size_t)(b * N_C + c)) * N_H + h) * 4096;
#pragma unroll
        for (int ns = 0; ns < 4; ns++) {
            bf16x8 b0 = *(const bf16x8*)&Ql[(ns * 16 + l16) * NP + q * 8];
            bf16x8 b1 = *(const bf16x8*)&Ql[(ns * 16 + l16) * NP + 32 + q * 8];
            f32x4 z = {0.f, 0.f, 0.f, 0.f};
            f32x4 s = mfma16(a0, b0, z);
            s = mfma16(a1, b1, s);
            bf16x4 p;
#pragma unroll
            for (int r = 0; r < 4; r++) p[r] = (bf16)s[r];
#pragma unroll
            for (int r = 0; r < 4; r++)
                Qrd[tb + (w * 16 + q * 4 + r) * 64 + ns * 16 + l16] = p[r];
            *(bf16x4*)&QT[(ns * 16 + l16) * NP + w * 16 + q * 4] = p;  // [i'][u]
            b0 = *(const bf16x8*)&El[(ns * 16 + l16) * NP + q * 8];
            b1 = *(const bf16x8*)&El[(ns * 16 + l16) * NP + 32 + q * 8];
            f32x4 s2 = mfma16(a0, b0, z);
            s2 = mfma16(a1, b1, s2);
#pragma unroll
            for (int r = 0; r < 4; r++) p[r] = (bf16)s2[r];
            *(bf16x4*)&ET[(ns * 16 + l16) * NP + w * 16 + q * 4] = p;  // [i][u]
        }
        __syncthreads();
        {
            const bf16x8 qa0 = *(const bf16x8*)&QT[(w * 16 + l16) * NP + q * 8];
            const bf16x8 qa1 = *(const bf16x8*)&QT[(w * 16 + l16) * NP + 32 + q * 8];
#pragma unroll
            for (int ns = 0; ns < 4; ns++) {
                const bf16x8 e0 = *(const bf16x8*)&ET[(ns * 16 + l16) * NP + q * 8];
                const bf16x8 e1 = *(const bf16x8*)&ET[(ns * 16 + l16) * NP + 32 + q * 8];
                dacc[ns] = mfma16(qa0, e0, dacc[ns]);
                dacc[ns] = mfma16(qa1, e1, dacc[ns]);
            }
        }
        {
            const bf16x8 v0 = *(const bf16x8*)&ET[row * NP + col];
            const bf16x8 v1 = *(const bf16x8*)&ET[row * NP + col + 8];
            bf16* d = Erd + tb + row * 64 + col;
            *(bf16x8*)d = v0;
            *(bf16x8*)(d + 8) = v1;
        }
        __syncthreads();
    }
#pragma unroll
    for (int ns = 0; ns < 4; ns++) {
        bf16x4 p;
#pragma unroll
        for (int r = 0; r < 4; r++) p[r] = (bf16)dacc[ns][r];
        *(bf16x4*)&QT[(ns * 16 + l16) * NP + w * 16 + q * 4] = p;
    }
    __syncthreads();
    {
        bf16* dst = dGq + (((size_t)(b * N_C + c)) * 4 + qt) * 4096 + row * 64 + col;
        *(bf16x8*)dst       = *(const bf16x8*)&QT[row * NP + col];
        *(bf16x8*)(dst + 8) = *(const bf16x8*)&QT[row * NP + col + 8];
    }
}

// ---------------------------------------------------------------------------
// K2: fused fold+scan, ONE block per (b,c):
//   Gc[b,c] = sum_{c'<c} sum_qt dGq[b,c',qt]   (reads quarters directly)
// Batch-8 register prefetch of independent 16 B tile-slices (<=124 loads).
// Grid (D_B, N_C): linear%8 = b (XCD-local).
// ---------------------------------------------------------------------------
__global__ __launch_bounds__(256, 4) void k_scanq(const bf16* __restrict__ dGq,
                                                  bf16* __restrict__ Gc)
{
    const int b = blockIdx.x, c = blockIdx.y;
    const int tid = threadIdx.x;
    float run[16];
#pragma unroll
    for (int k = 0; k < 16; k++) run[k] = 0.f;
    const bf16* base = dGq + (size_t)b * N_C * 4 * 4096 + tid * 16;
    const int nt = 4 * c;
    int t = 0;
    for (; t + 8 <= nt; t += 8) {
        bf16x8 v[8][2];
#pragma unroll
        for (int j = 0; j < 8; j++) {
            v[j][0] = *(const bf16x8*)(base + (size_t)(t + j) * 4096);
            v[j][1] = *(const bf16x8*)(base + (size_t)(t + j) * 4096 + 8);
        }
#pragma unroll
        for (int j = 0; j < 8; j++)
#pragma unroll
            for (int k = 0; k < 8; k++) {
                run[k] += (float)v[j][0][k];
                run[8 + k] += (float)v[j][1][k];
            }
    }
    for (; t < nt; t++) {
        const bf16x8 v0 = *(const bf16x8*)(base + (size_t)t * 4096);
        const bf16x8 v1 = *(const bf16x8*)(base + (size_t)t * 4096 + 8);
#pragma unroll
        for (int k = 0; k < 8; k++) { run[k] += (float)v0[k]; run[8 + k] += (float)v1[k]; }
    }
    bf16x8 o0, o1;
#pragma unroll
    for (int k = 0; k < 8; k++) { o0[k] = (bf16)run[k]; o1[k] = (bf16)run[8 + k]; }
    bf16* dst = Gc + (size_t)(b * N_C + c) * 4096 + tid * 16;
    *(bf16x8*)dst = o0;
    *(bf16x8*)(dst + 8) = o1;
}

// ---------------------------------------------------------------------------
// One head of the K3 loop, fully static (NU = 2 or 4). Writes S to the given
// slab, reads it back (same-wave in-order DS), accumulates the nh-half of
// S*Er (2 output-column tiles).
// ---------------------------------------------------------------------------
template <int NU>
static __device__ __forceinline__ void head_iter(
    const bf16* __restrict__ Qh, const bf16* __restrict__ Eh,
    bf16* __restrict__ Sw, const bf16x8 ra0, const bf16x8 ra1,
    int l16, int q, int tbase, int io, f32x4 (&acc)[2])
{
#pragma unroll
    for (int nu = 0; nu < NU; nu++) {
        const bf16x8 b0 = *(const bf16x8*)&Qh[(nu * 16 + l16) * 64 + q * 8];
        const bf16x8 b1 = *(const bf16x8*)&Qh[(nu * 16 + l16) * 64 + 32 + q * 8];
        f32x4 z = {0.f, 0.f, 0.f, 0.f};
        f32x4 sv = mfma16(ra0, b0, z);
        sv = mfma16(ra1, b1, sv);
        const int u_loc = nu * 16 + l16;
#pragma unroll
        for (int r = 0; r < 4; r++) {
            const int t_loc = tbase + q * 4 + r;
            Sw[(q * 4 + r) * NP + u_loc] = (u_loc <= t_loc) ? (bf16)sv[r] : (bf16)0.f;
        }
    }
    const bf16x8 sa0 = *(const bf16x8*)&Sw[l16 * NP + q * 8];
#pragma unroll
    for (int ns = 0; ns < 2; ns++) {
        const bf16x8 e0 = *(const bf16x8*)&Eh[(io + ns * 16 + l16) * 64 + q * 8];
        acc[ns] = mfma16(sa0, e0, acc[ns]);
    }
    if (NU == 4) {
        const bf16x8 sa1 = *(const bf16x8*)&Sw[l16 * NP + 32 + q * 8];
#pragma unroll
        for (int ns = 0; ns < 2; ns++) {
            const bf16x8 e1 = *(const bf16x8*)&Eh[(io + ns * 16 + l16) * 64 + 32 + q * 8];
            acc[ns] = mfma16(sa1, e1, acc[ns]);
        }
    }
}

// ---------------------------------------------------------------------------
// K3: block (b, c, z) with z=(half, nh): out rows [c*64+half*32, +32),
// cols [nh*32, +32). S-build duplicated per nh (cheap, MfmaUtil ~1%); Eh/Gc
// reads halve per block. 1024 blocks -> 4 blocks/CU -> 16 waves/CU: 2x the
// latency hiding of R10/R12. ONE barrier. Grid (D_B, N_C, 4): linear%8 = b.
// ---------------------------------------------------------------------------
__global__ __launch_bounds__(256, 4) void k_out(
    const bf16* __restrict__ Gc, const bf16* __restrict__ Rbf,
    const bf16* __restrict__ Qrd, const bf16* __restrict__ Erd,
    float* __restrict__ out)
{
    __shared__ bf16 Sl[4 * 2 * 16 * NP];  // per-wave ping-pong S slabs
    __shared__ float Ob[32 * 33];         // h-group reduction (32 cols)
    const int b = blockIdx.x, c = blockIdx.y, z = blockIdx.z;
    const int half = z >> 1, nh = z & 1;
    const int tid = threadIdx.x;
    const int w = tid >> 6, l = tid & 63, q = l >> 4, l16 = l & 15;
    const int s = w & 1, g = w >> 1;

    // A-frags: R rows t = c*64 + half*32 + s*16 + l16
    const int trow = c * 64 + half * 32 + s * 16 + l16;
    const bf16x8 ra0 = *(const bf16x8*)&Rbf[((size_t)b * N_T + trow) * NN + q * 8];
    const bf16x8 ra1 = *(const bf16x8*)&Rbf[((size_t)b * N_T + trow) * NN + 32 + q * 8];

    bf16* Sw0 = Sl + (w * 2 + 0) * 16 * NP;
    bf16* Sw1 = Sl + (w * 2 + 1) * 16 * NP;
    const int tbase = half * 32 + s * 16;
    const int io = nh * 32;   // output-column base (i-rows of Erd/Gc)
    const size_t hb = (((size_t)(b * N_C + c)) * N_H + g * 4) * 4096;
    const bf16* Qg = Qrd + hb;   // 4 heads, 4096 apart
    const bf16* Eg = Erd + hb;
    f32x4 acc[2];
#pragma unroll
    for (int ns = 0; ns < 2; ns++) { f32x4 zz = {0.f, 0.f, 0.f, 0.f}; acc[ns] = zz; }

    if (half) {
#pragma unroll
        for (int hh = 0; hh < 4; hh++)
            head_iter<4>(Qg + (size_t)hh * 4096, Eg + (size_t)hh * 4096,
                         (hh & 1) ? Sw1 : Sw0, ra0, ra1, l16, q, tbase, io, acc);
    } else {
#pragma unroll
        for (int hh = 0; hh < 4; hh++)
            head_iter<2>(Qg + (size_t)hh * 4096, Eg + (size_t)hh * 4096,
                         (hh & 1) ? Sw1 : Sw0, ra0, ra1, l16, q, tbase, io, acc);
    }

    if (g == 1) {
        // prefix term: O += R_t * Gcum, B storage [n=i][k=i'] = Gc (global)
        const bf16* Gt = Gc + (size_t)(b * N_C + c) * 4096;
#pragma unroll
        for (int ns = 0; ns < 2; ns++) {
            const bf16x8 g0 = *(const bf16x8*)&Gt[(io + ns * 16 + l16) * 64 + q * 8];
            const bf16x8 g1 = *(const bf16x8*)&Gt[(io + ns * 16 + l16) * 64 + 32 + q * 8];
            acc[ns] = mfma16(ra0, g0, acc[ns]);
            acc[ns] = mfma16(ra1, g1, acc[ns]);
        }
    }
    if (g == 0) {
#pragma unroll
        for (int ns = 0; ns < 2; ns++)
#pragma unroll
            for (int r = 0; r < 4; r++)
                Ob[(s * 16 + q * 4 + r) * 33 + ns * 16 + l16] = acc[ns][r];
    }
    __syncthreads();
    if (g == 1) {
        const int t0 = c * 64 + half * 32;
#pragma unroll
        for (int ns = 0; ns < 2; ns++)
#pragma unroll
            for (int r = 0; r < 4; r++) {
                const float sum = acc[ns][r] + Ob[(s * 16 + q * 4 + r) * 33 + ns * 16 + l16];
                out[((size_t)b * N_T + t0 + s * 16 + q * 4 + r) * NN + io + ns * 16 + l16] = sum;
            }
    }
}

// ---------------------------------------------------------------------------
extern "C" void kernel_launch(void* const* d_in, const int* in_sizes, int n_in,
                              void* d_out, int out_size, void* d_ws, size_t ws_size,
                              hipStream_t stream) {
    const float* rp = (const float*)d_in[0];   // (8, 2048, 64) fp32
    const float* Qm = (const float*)d_in[1];   // (8, 64, 64)
    const float* Em = (const float*)d_in[2];   // (8, 64, 64)
    float* out = (float*)d_out;                // (8, 2048, 64) fp32

    // ws: dGq 8.4 MB + Gc 2.1 MB + Rbf 2 MB + Qrd 16.8 MB + Erd 16.8 MB
    bf16* dGq = (bf16*)d_ws;
    bf16* Gc  = dGq + (size_t)D_B * N_C * 4 * 4096;
    bf16* Rbf = Gc + (size_t)D_B * N_C * 4096;
    bf16* Qrd = Rbf + (size_t)D_B * N_T * NN;
    bf16* Erd = Qrd + (size_t)D_B * N_C * N_H * 4096;

    k_dg<<<dim3(D_B, N_C, 4), 256, 0, stream>>>(rp, Qm, Em, dGq, Rbf, Qrd, Erd);
    k_scanq<<<dim3(D_B, N_C), 256, 0, stream>>>(dGq, Gc);
    k_out<<<dim3(D_B, N_C, 4), 256, 0, stream>>>(Gc, Rbf, Qrd, Erd, out);
}

// Round 14
// 103.107 us; speedup vs baseline: 1.3245x; 1.3245x over previous
//
#include <hip/hip_runtime.h>

// Problem constants
#define D_B 8
#define N_T 2048
#define NN  64
#define N_H 8
#define N_C 32   // u-chunks of 64
#define NP  72   // padded LDS row stride (bf16): 144 B rows, 16B-aligned, 2-way alias (free)

typedef __bf16 bf16;
typedef bf16 bf16x8 __attribute__((ext_vector_type(8)));
typedef bf16 bf16x4 __attribute__((ext_vector_type(4)));
typedef float f32x4 __attribute__((ext_vector_type(4)));

static __device__ __forceinline__ f32x4 mfma16(bf16x8 a, bf16x8 b, f32x4 c) {
    // a_frag[j] = A[lane&15][(lane>>4)*8+j]; b_frag[j] = B[(lane>>4)*8+j][lane&15]
    // d[r] = D[(lane>>4)*4+r][lane&15]
    return __builtin_amdgcn_mfma_f32_16x16x32_bf16(a, b, c, 0, 0, 0);
}

static __device__ __forceinline__ bf16x8 ldcvt8(const float* p) {
    const f32x4 v0 = *(const f32x4*)p;
    const f32x4 v1 = *(const f32x4*)(p + 4);
    bf16x8 r;
#pragma unroll
    for (int k = 0; k < 4; k++) { r[k] = (bf16)v0[k]; r[4 + k] = (bf16)v1[k]; }
    return r;
}

// ---------------------------------------------------------------------------
// K1: block (b, c, qt) handles heads {2qt, 2qt+1}:
//   Qrd[b,c,h][u][i'] (direct store), Erd[b,c,h][i][u] (LDS-transposed flush),
//   dGq[b,c,qt][i][i'] (pre-transposed bf16), Rbf (qt==0).
// R A-frags direct from global fp32. 36.9 KB LDS -> 4 blocks/CU.
// Grid (D_B, N_C, 4): linear%8 = b (XCD-local).
// ---------------------------------------------------------------------------
__global__ __launch_bounds__(256, 4) void k_dg(
    const float* __restrict__ rp, const float* __restrict__ Qm,
    const float* __restrict__ Em,
    bf16* __restrict__ dGq, bf16* __restrict__ Rbf,
    bf16* __restrict__ Qrd, bf16* __restrict__ Erd)
{
    __shared__ bf16 Ql[64 * NP];   // Q_h [i'][j]
    __shared__ bf16 El[64 * NP];   // E_h [i][j]
    __shared__ bf16 QT[64 * NP];   // Qr tile [i'][u]; dG [i][i'] staging at tail
    __shared__ bf16 ET[64 * NP];   // Er tile [i][u]
    const int b = blockIdx.x, c = blockIdx.y, qt = blockIdx.z;
    const int tid = threadIdx.x;
    const int w = tid >> 6, l = tid & 63, q = l >> 4, l16 = l & 15;
    const int row = tid >> 2, col = (tid & 3) * 16;

    // R A-frags straight from global fp32 (rows u = c*64 + w*16 + l16)
    const float* rrow = rp + ((size_t)b * N_T + c * 64 + w * 16 + l16) * NN;
    const bf16x8 a0 = ldcvt8(rrow + q * 8);
    const bf16x8 a1 = ldcvt8(rrow + 32 + q * 8);

    if (qt == 0) {
        const float* src = rp + ((size_t)b * N_T + c * 64 + row) * NN + col;
        bf16* d = Rbf + ((size_t)b * N_T + c * 64 + row) * NN + col;
        *(bf16x8*)d       = ldcvt8(src);
        *(bf16x8*)(d + 8) = ldcvt8(src + 8);
    }

    f32x4 dacc[4];
#pragma unroll
    for (int ns = 0; ns < 4; ns++) { f32x4 z = {0.f, 0.f, 0.f, 0.f}; dacc[ns] = z; }

    for (int hh = 0; hh < 2; hh++) {
        const int h = qt * 2 + hh;
        {
            const float* qs = Qm + (size_t)h * 4096 + row * 64 + col;
            const float* es = Em + (size_t)h * 4096 + row * 64 + col;
            *(bf16x8*)&Ql[row * NP + col]     = ldcvt8(qs);
            *(bf16x8*)&Ql[row * NP + col + 8] = ldcvt8(qs + 8);
            *(bf16x8*)&El[row * NP + col]     = ldcvt8(es);
            *(bf16x8*)&El[row * NP + col + 8] = ldcvt8(es + 8);
        }
        __syncthreads();
        const size_t tb = (((size_t)(b * N_C + c)) * N_H + h) * 4096;
#pragma unroll
        for (int ns = 0; ns < 4; ns++) {
            bf16x8 b0 = *(const bf16x8*)&Ql[(ns * 16 + l16) * NP + q * 8];
            bf16x8 b1 = *(const bf16x8*)&Ql[(ns * 16 + l16) * NP + 32 + q * 8];
            f32x4 z = {0.f, 0.f, 0.f, 0.f};
            f32x4 s = mfma16(a0, b0, z);
            s = mfma16(a1, b1, s);
            bf16x4 p;
#pragma unroll
            for (int r = 0; r < 4; r++) p[r] = (bf16)s[r];
#pragma unroll
            for (int r = 0; r < 4; r++)
                Qrd[tb + (w * 16 + q * 4 + r) * 64 + ns * 16 + l16] = p[r];
            *(bf16x4*)&QT[(ns * 16 + l16) * NP + w * 16 + q * 4] = p;  // [i'][u]
            b0 = *(const bf16x8*)&El[(ns * 16 + l16) * NP + q * 8];
            b1 = *(const bf16x8*)&El[(ns * 16 + l16) * NP + 32 + q * 8];
            f32x4 s2 = mfma16(a0, b0, z);
            s2 = mfma16(a1, b1, s2);
#pragma unroll
            for (int r = 0; r < 4; r++) p[r] = (bf16)s2[r];
            *(bf16x4*)&ET[(ns * 16 + l16) * NP + w * 16 + q * 4] = p;  // [i][u]
        }
        __syncthreads();
        {
            const bf16x8 qa0 = *(const bf16x8*)&QT[(w * 16 + l16) * NP + q * 8];
            const bf16x8 qa1 = *(const bf16x8*)&QT[(w * 16 + l16) * NP + 32 + q * 8];
#pragma unroll
            for (int ns = 0; ns < 4; ns++) {
                const bf16x8 e0 = *(const bf16x8*)&ET[(ns * 16 + l16) * NP + q * 8];
                const bf16x8 e1 = *(const bf16x8*)&ET[(ns * 16 + l16) * NP + 32 + q * 8];
                dacc[ns] = mfma16(qa0, e0, dacc[ns]);
                dacc[ns] = mfma16(qa1, e1, dacc[ns]);
            }
        }
        {
            const bf16x8 v0 = *(const bf16x8*)&ET[row * NP + col];
            const bf16x8 v1 = *(const bf16x8*)&ET[row * NP + col + 8];
            bf16* d = Erd + tb + row * 64 + col;
            *(bf16x8*)d = v0;
            *(bf16x8*)(d + 8) = v1;
        }
        __syncthreads();
    }
#pragma unroll
    for (int ns = 0; ns < 4; ns++) {
        bf16x4 p;
#pragma unroll
        for (int r = 0; r < 4; r++) p[r] = (bf16)dacc[ns][r];
        *(bf16x4*)&QT[(ns * 16 + l16) * NP + w * 16 + q * 4] = p;
    }
    __syncthreads();
    {
        bf16* dst = dGq + (((size_t)(b * N_C + c)) * 4 + qt) * 4096 + row * 64 + col;
        *(bf16x8*)dst       = *(const bf16x8*)&QT[row * NP + col];
        *(bf16x8*)(dst + 8) = *(const bf16x8*)&QT[row * NP + col + 8];
    }
}

// ---------------------------------------------------------------------------
// K2: fold the 4 head-quarters: dG8[b,c] = sum_qt dGq[b,c,qt].
// 4 independent 16 B loads/thread; grid (D_B, N_C): linear%8 = b.
// ---------------------------------------------------------------------------
__global__ __launch_bounds__(256, 4) void k_fold(const bf16* __restrict__ dGq,
                                                 bf16* __restrict__ dG8)
{
    const int b = blockIdx.x, c = blockIdx.y;
    const size_t base = ((size_t)(b * N_C + c)) * 4 * 4096 + threadIdx.x * 16;
    float s[16];
#pragma unroll
    for (int k = 0; k < 16; k++) s[k] = 0.f;
#pragma unroll
    for (int qt = 0; qt < 4; qt++) {
        const bf16x8 v0 = *(const bf16x8*)(dGq + base + (size_t)qt * 4096);
        const bf16x8 v1 = *(const bf16x8*)(dGq + base + (size_t)qt * 4096 + 8);
#pragma unroll
        for (int k = 0; k < 8; k++) { s[k] += (float)v0[k]; s[8 + k] += (float)v1[k]; }
    }
    bf16x8 o0, o1;
#pragma unroll
    for (int k = 0; k < 8; k++) { o0[k] = (bf16)s[k]; o1[k] = (bf16)s[8 + k]; }
    bf16* dst = dG8 + (size_t)(b * N_C + c) * 4096 + threadIdx.x * 16;
    *(bf16x8*)dst = o0;
    *(bf16x8*)(dst + 8) = o1;
}

// ---------------------------------------------------------------------------
// One head of the K3 loop, fully static (NU = 2 or 4). Writes S to the given
// slab, reads it back (same-wave in-order DS), accumulates S*Er.
// ---------------------------------------------------------------------------
template <int NU>
static __device__ __forceinline__ void head_iter(
    const bf16* __restrict__ Qh, const bf16* __restrict__ Eh,
    bf16* __restrict__ Sw, const bf16x8 ra0, const bf16x8 ra1,
    int l16, int q, int tbase, f32x4 (&acc)[4])
{
#pragma unroll
    for (int nu = 0; nu < NU; nu++) {
        const bf16x8 b0 = *(const bf16x8*)&Qh[(nu * 16 + l16) * 64 + q * 8];
        const bf16x8 b1 = *(const bf16x8*)&Qh[(nu * 16 + l16) * 64 + 32 + q * 8];
        f32x4 z = {0.f, 0.f, 0.f, 0.f};
        f32x4 sv = mfma16(ra0, b0, z);
        sv = mfma16(ra1, b1, sv);
        const int u_loc = nu * 16 + l16;
#pragma unroll
        for (int r = 0; r < 4; r++) {
            const int t_loc = tbase + q * 4 + r;
            Sw[(q * 4 + r) * NP + u_loc] = (u_loc <= t_loc) ? (bf16)sv[r] : (bf16)0.f;
        }
    }
    const bf16x8 sa0 = *(const bf16x8*)&Sw[l16 * NP + q * 8];
#pragma unroll
    for (int ns = 0; ns < 4; ns++) {
        const bf16x8 e0 = *(const bf16x8*)&Eh[(ns * 16 + l16) * 64 + q * 8];
        acc[ns] = mfma16(sa0, e0, acc[ns]);
    }
    if (NU == 4) {
        const bf16x8 sa1 = *(const bf16x8*)&Sw[l16 * NP + 32 + q * 8];
#pragma unroll
        for (int ns = 0; ns < 4; ns++) {
            const bf16x8 e1 = *(const bf16x8*)&Eh[(ns * 16 + l16) * 64 + 32 + q * 8];
            acc[ns] = mfma16(sa1, e1, acc[ns]);
        }
    }
}

// ---------------------------------------------------------------------------
// K3: block (b, c, half) computes out rows [c*64 + half*32, +32).
// Register scan of <=31 folded tiles (batch-4); head loop fully unrolled with
// constexpr NU and ping-pong per-wave S slabs. Gb publish + one barrier
// deferred to the end. Grid (D_B, N_C, 2): linear%8 = b.
// ---------------------------------------------------------------------------
__global__ __launch_bounds__(256, 4) void k_out(
    const bf16* __restrict__ dG8, const bf16* __restrict__ Rbf,
    const bf16* __restrict__ Qrd, const bf16* __restrict__ Erd,
    float* __restrict__ out)
{
    __shared__ bf16 Gb[64 * NP];          // Gcum [i][i'] (written AFTER head loop)
    __shared__ bf16 Sl[4 * 2 * 16 * NP];  // per-wave ping-pong S slabs
    __shared__ float Ob[32 * 65];         // h-group reduction
    const int b = blockIdx.x, c = blockIdx.y, half = blockIdx.z;
    const int tid = threadIdx.x;
    const int w = tid >> 6, l = tid & 63, q = l >> 4, l16 = l & 15;
    const int s = w & 1, g = w >> 1;

    // A-frags: R rows t = c*64 + half*32 + s*16 + l16
    const int trow = c * 64 + half * 32 + s * 16 + l16;
    const bf16x8 ra0 = *(const bf16x8*)&Rbf[((size_t)b * N_T + trow) * NN + q * 8];
    const bf16x8 ra1 = *(const bf16x8*)&Rbf[((size_t)b * N_T + trow) * NN + 32 + q * 8];

    // ---- scan (registers only; no LDS, no barrier yet), batch-4 prefetch
    float run[16];
#pragma unroll
    for (int k = 0; k < 16; k++) run[k] = 0.f;
    {
        const bf16* base = dG8 + (size_t)b * N_C * 4096 + tid * 16;
        int t = 0;
        for (; t + 4 <= c; t += 4) {
            bf16x8 v[4][2];
#pragma unroll
            for (int j = 0; j < 4; j++) {
                v[j][0] = *(const bf16x8*)(base + (size_t)(t + j) * 4096);
                v[j][1] = *(const bf16x8*)(base + (size_t)(t + j) * 4096 + 8);
            }
#pragma unroll
            for (int j = 0; j < 4; j++)
#pragma unroll
                for (int k = 0; k < 8; k++) {
                    run[k] += (float)v[j][0][k];
                    run[8 + k] += (float)v[j][1][k];
                }
        }
        for (; t < c; t++) {
            const bf16x8 v0 = *(const bf16x8*)(base + (size_t)t * 4096);
            const bf16x8 v1 = *(const bf16x8*)(base + (size_t)t * 4096 + 8);
#pragma unroll
            for (int k = 0; k < 8; k++) { run[k] += (float)v0[k]; run[8 + k] += (float)v1[k]; }
        }
    }

    // ---- head loop (barrier-free; ping-pong per-wave S slabs; static NU)
    bf16* Sw0 = Sl + (w * 2 + 0) * 16 * NP;
    bf16* Sw1 = Sl + (w * 2 + 1) * 16 * NP;
    const int tbase = half * 32 + s * 16;
    const size_t hb = (((size_t)(b * N_C + c)) * N_H + g * 4) * 4096;
    const bf16* Qg = Qrd + hb;   // 4 heads, 4096 apart
    const bf16* Eg = Erd + hb;
    f32x4 acc[4];
#pragma unroll
    for (int ns = 0; ns < 4; ns++) { f32x4 z = {0.f, 0.f, 0.f, 0.f}; acc[ns] = z; }

    if (half) {
#pragma unroll
        for (int hh = 0; hh < 4; hh++)
            head_iter<4>(Qg + (size_t)hh * 4096, Eg + (size_t)hh * 4096,
                         (hh & 1) ? Sw1 : Sw0, ra0, ra1, l16, q, tbase, acc);
    } else {
#pragma unroll
        for (int hh = 0; hh < 4; hh++)
            head_iter<2>(Qg + (size_t)hh * 4096, Eg + (size_t)hh * 4096,
                         (hh & 1) ? Sw1 : Sw0, ra0, ra1, l16, q, tbase, acc);
    }

    // ---- publish Gb (from scan regs) + Ob (g==0 partials); ONE barrier
    {
        // elem idx = tid*16+k -> i = tid>>2, i' = (tid&3)*16 + k
        bf16x8 o0, o1;
#pragma unroll
        for (int k = 0; k < 8; k++) { o0[k] = (bf16)run[k]; o1[k] = (bf16)run[8 + k]; }
        *(bf16x8*)&Gb[(tid >> 2) * NP + (tid & 3) * 16] = o0;
        *(bf16x8*)&Gb[(tid >> 2) * NP + (tid & 3) * 16 + 8] = o1;
    }
    if (g == 0) {
#pragma unroll
        for (int ns = 0; ns < 4; ns++)
#pragma unroll
            for (int r = 0; r < 4; r++)
                Ob[(s * 16 + q * 4 + r) * 65 + ns * 16 + l16] = acc[ns][r];
    }
    __syncthreads();
    if (g == 1) {
        // prefix term: O += R_t * Gcum, B storage [n=i][k=i'] = Gb
#pragma unroll
        for (int ns = 0; ns < 4; ns++) {
            const bf16x8 g0 = *(const bf16x8*)&Gb[(ns * 16 + l16) * NP + q * 8];
            const bf16x8 g1 = *(const bf16x8*)&Gb[(ns * 16 + l16) * NP + 32 + q * 8];
            acc[ns] = mfma16(ra0, g0, acc[ns]);
            acc[ns] = mfma16(ra1, g1, acc[ns]);
        }
        const int t0 = c * 64 + half * 32;
#pragma unroll
        for (int ns = 0; ns < 4; ns++)
#pragma unroll
            for (int r = 0; r < 4; r++) {
                const float sum = acc[ns][r] + Ob[(s * 16 + q * 4 + r) * 65 + ns * 16 + l16];
                out[((size_t)b * N_T + t0 + s * 16 + q * 4 + r) * NN + ns * 16 + l16] = sum;
            }
    }
}

// ---------------------------------------------------------------------------
extern "C" void kernel_launch(void* const* d_in, const int* in_sizes, int n_in,
                              void* d_out, int out_size, void* d_ws, size_t ws_size,
                              hipStream_t stream) {
    const float* rp = (const float*)d_in[0];   // (8, 2048, 64) fp32
    const float* Qm = (const float*)d_in[1];   // (8, 64, 64)
    const float* Em = (const float*)d_in[2];   // (8, 64, 64)
    float* out = (float*)d_out;                // (8, 2048, 64) fp32

    // ws: dGq 8.4 MB + Rbf 2 MB + Qrd 16.8 MB + Erd 16.8 MB + dG8 2.1 MB
    bf16* dGq = (bf16*)d_ws;
    bf16* Rbf = dGq + (size_t)D_B * N_C * 4 * 4096;
    bf16* Qrd = Rbf + (size_t)D_B * N_T * NN;
    bf16* Erd = Qrd + (size_t)D_B * N_C * N_H * 4096;
    bf16* dG8 = Erd + (size_t)D_B * N_C * N_H * 4096;

    k_dg<<<dim3(D_B, N_C, 4), 256, 0, stream>>>(rp, Qm, Em, dGq, Rbf, Qrd, Erd);
    k_fold<<<dim3(D_B, N_C), 256, 0, stream>>>(dGq, dG8);
    k_out<<<dim3(D_B, N_C, 2), 256, 0, stream>>>(dG8, Rbf, Qrd, Erd, out);
}